// Round 5
// baseline (389.638 us; speedup 1.0000x reference)
//
#include <hip/hip_runtime.h>
#include <hip/hip_fp16.h>

// Problem constants (fixed by the reference setup):
//   N = 117000 vocab rows, BT = B*T = 4*64 = 256, E = 500000 edges (in_sizes[1])
#define NN 117000
#define BT 256

// Scan decomposition: 115 blocks x 256 threads x 4 elems = 117760 slots >= NN
#define SCAN_CHUNK 1024
#define SCAN_NB ((NN + SCAN_CHUNK - 1) / SCAN_CHUNK)   // 115
#define SCAN_P2_T 128                                   // >= SCAN_NB

// Fused gather+finalize geometry: 32 rows per block, 8 waves (512 threads),
// each wave owns 4 consecutive rows (their CSR edge ranges are contiguous).
#define ROWS_PB 32
#define LDS_STRIDE 257   // odd stride: epilogue reads conflict-free, writes 2-way (free)

union U8 { uint2 u; __half2 h[2]; };

__device__ inline float readlane_f(float x, int l) {
    return __int_as_float(__builtin_amdgcn_readlane(__float_as_int(x), l));
}

// ===================== CSR build =====================

// count[r] += 1 for each edge
__global__ void hist_kernel(const int* __restrict__ row, int* __restrict__ count, int E) {
    int e = blockIdx.x * blockDim.x + threadIdx.x;
    if (e < E) atomicAdd(&count[row[e]], 1);
}

// Phase 1: per-block sum of each 1024-count chunk.
__global__ void scan_phase1(const int* __restrict__ count, int* __restrict__ block_sums) {
    __shared__ int s[256];
    int base = blockIdx.x * SCAN_CHUNK + threadIdx.x * 4;
    int sum = 0;
#pragma unroll
    for (int j = 0; j < 4; ++j) {
        int idx = base + j;
        if (idx < NN) sum += count[idx];
    }
    s[threadIdx.x] = sum;
    __syncthreads();
    for (int off = 128; off > 0; off >>= 1) {
        if (threadIdx.x < off) s[threadIdx.x] += s[threadIdx.x + off];
        __syncthreads();
    }
    if (threadIdx.x == 0) block_sums[blockIdx.x] = s[0];
}

// Phase 2: single small block — exclusive scan of the 115 block sums,
// and write row_ptr[NN] = E.
__global__ void scan_phase2(int* __restrict__ block_sums, int* __restrict__ row_ptr) {
    __shared__ int s[SCAN_P2_T];
    int t = threadIdx.x;
    int v = (t < SCAN_NB) ? block_sums[t] : 0;
    s[t] = v;
    __syncthreads();
    for (int off = 1; off < SCAN_P2_T; off <<= 1) {
        int u = (t >= off) ? s[t - off] : 0;
        __syncthreads();
        s[t] += u;
        __syncthreads();
    }
    if (t < SCAN_NB) block_sums[t] = (t == 0) ? 0 : s[t - 1];  // exclusive offsets
    if (t == SCAN_P2_T - 1) row_ptr[NN] = s[SCAN_NB - 1];      // total == E
}

// Phase 3: in-place exclusive scan of counts within each chunk + block offset.
__global__ void scan_phase3(int* __restrict__ row_ptr, const int* __restrict__ block_offs,
                            int* __restrict__ cursor) {
    __shared__ int s[256];
    int base = blockIdx.x * SCAN_CHUNK + threadIdx.x * 4;
    int v[4];
    int sum = 0;
#pragma unroll
    for (int j = 0; j < 4; ++j) {
        int idx = base + j;
        v[j] = (idx < NN) ? row_ptr[idx] : 0;
        sum += v[j];
    }
    s[threadIdx.x] = sum;
    __syncthreads();
    for (int off = 1; off < 256; off <<= 1) {
        int u = (threadIdx.x >= off) ? s[threadIdx.x - off] : 0;
        __syncthreads();
        s[threadIdx.x] += u;
        __syncthreads();
    }
    int prefix = block_offs[blockIdx.x] + ((threadIdx.x == 0) ? 0 : s[threadIdx.x - 1]);
#pragma unroll
    for (int j = 0; j < 4; ++j) {
        int idx = base + j;
        if (idx < NN) {
            row_ptr[idx] = prefix;
            cursor[idx]  = prefix;
            prefix += v[j];
        }
    }
}

// Scatter edges into row-sorted order as packed {col, vv_bits} int2.
// Order within a row is nondeterministic — only changes fp32 summation order.
__global__ void scatter_kernel(const int* __restrict__ row, const int* __restrict__ col,
                               const float* __restrict__ vv, int* __restrict__ cursor,
                               int2* __restrict__ edge_s, int E) {
    int e = blockIdx.x * blockDim.x + threadIdx.x;
    if (e >= E) return;
    int p = atomicAdd(&cursor[row[e]], 1);
    edge_s[p] = make_int2(col[e], __float_as_int(vv[e]));
}

// ===================== main pipeline =====================

// fp16 transpose: xT[i*BT + bt] = (half)logits[bt*NN + i]
// Tile: 32 i x 64 bt. NT loads: logits is a single-use stream — keep LLC for xT.
__global__ void transpose_h_kernel(const float* __restrict__ logits, __half* __restrict__ xT) {
    __shared__ float s[64][33];   // [bt_local][i_local]
    int tx = threadIdx.x & 31;
    int ty = threadIdx.x >> 5;    // 0..7
    int i0  = blockIdx.x * 32;
    int bt0 = blockIdx.y * 64;
    int i = i0 + tx;
    if (i < NN) {
#pragma unroll
        for (int r = 0; r < 8; ++r) {
            int bt = bt0 + ty + r * 8;
            s[ty + r * 8][tx] =
                __builtin_nontemporal_load(&logits[(size_t)bt * NN + i]);   // coalesced over i
        }
    }
    __syncthreads();
#pragma unroll
    for (int r = 0; r < 4; ++r) {
        int il = ty + r * 8;
        int i2 = i0 + il;
        if (i2 < NN) {
            __half2 h = __floats2half2_rn(s[2 * tx][il], s[2 * tx + 1][il]);
            ((__half2*)(xT + (size_t)i2 * BT + bt0))[tx] = h;  // coalesced over bt
        }
    }
}

// Fused gather + normalize + transpose + add + store.
// 8 waves x 4 consecutive rows per block; wave streams its contiguous CSR range
// with a 4-deep gather pipeline running across row boundaries.
// T14: the 16 epilogue logits values per thread are prefetched into registers at
// kernel entry (addresses independent of the gather) — the 120 MB logits read
// completes under the gather phase's latency stalls. NT loads/stores keep the
// single-use logits/out streams from evicting xT out of the Infinity Cache.
__global__ void row_gather_fused_kernel(const int* __restrict__ row_ptr,
                                        const int2* __restrict__ edge_s,
                                        const __half* __restrict__ xT,
                                        const float* __restrict__ logits,
                                        float* __restrict__ out) {
    __shared__ float s[ROWS_PB][LDS_STRIDE];
    int wave = threadIdx.x >> 6;   // 0..7
    int lane = threadIdx.x & 63;
    int i0 = blockIdx.x * ROWS_PB;
    int iw = i0 + wave * 4;        // first row of this wave
    const uint2* xT2 = (const uint2*)xT;   // 64 uint2 per row (256 halves)

    // ---- epilogue coords + async logits prefetch (registers) ----
    int tx = threadIdx.x & 31;
    int ty = threadIdx.x >> 5;     // 0..15
    int ie = i0 + tx;
    bool ie_ok = (ie < NN);
    float lg[16];
    if (ie_ok) {
#pragma unroll
        for (int r = 0; r < 16; ++r) {
            int bt = r * 16 + ty;
            lg[r] = __builtin_nontemporal_load(&logits[(size_t)bt * NN + ie]);
        }
    }

    if (iw < NN) {
        // row_ptr[iw .. iw+4] in one shot (clamped; row_ptr[NN] == E)
        int rp = 0;
        if (lane < 5) {
            int idx = iw + lane;
            if (idx > NN) idx = NN;
            rp = row_ptr[idx];
        }
        int kw0 = __shfl(rp, 0);
        int b0  = __shfl(rp, 1);
        int b1  = __shfl(rp, 2);
        int b2  = __shfl(rp, 3);
        int b3  = __shfl(rp, 4);
        int kw1 = b3;

        float4 acc = make_float4(0.f, 0.f, 0.f, 0.f);
        float rs = 0.f;
        int r_cur = 0;
        int next_b = b0;

#define FINALIZE_ROW() do {                                                   \
            float inv = (rs > 0.f) ? (1.0f / rs) : 0.f;                       \
            int rl = (wave << 2) + r_cur;                                     \
            s[rl][0 * 64 + lane] = acc.x * inv;                               \
            s[rl][1 * 64 + lane] = acc.y * inv;                               \
            s[rl][2 * 64 + lane] = acc.z * inv;                               \
            s[rl][3 * 64 + lane] = acc.w * inv;                               \
            acc = make_float4(0.f, 0.f, 0.f, 0.f);                            \
            rs = 0.f;                                                         \
            ++r_cur;                                                          \
            next_b = (r_cur == 1) ? b1 : ((r_cur == 2) ? b2 : b3);            \
        } while (0)

        // leading empty rows (defensive; setup guarantees none)
        while (r_cur < 4 && next_b == kw0) FINALIZE_ROW();

        for (int kb = kw0; kb < kw1; kb += 64) {
            int nk = min(64, kw1 - kb);
            int2 ed = make_int2(0, 0);
            if (lane < nk) ed = edge_s[kb + lane];   // one coalesced load per chunk
            int   ccol = ed.x;
            float cval = __int_as_float(ed.y);

            uint2 p0 = make_uint2(0u, 0u), p1 = p0, p2 = p0, p3 = p0;
#define ISSUE(dst, jj) do {                                                   \
                if ((jj) < nk) {                                              \
                    int cn = __builtin_amdgcn_readlane(ccol, (jj));           \
                    dst = xT2[(size_t)cn * (BT / 4) + lane];                  \
                }                                                             \
            } while (0)
            ISSUE(p0, 0); ISSUE(p1, 1); ISSUE(p2, 2); ISSUE(p3, 3);

#define CONSUME(pp, jj) do {                                                  \
                if ((jj) < nk) {                                              \
                    float v = readlane_f(cval, (jj));                         \
                    rs += v;                                                  \
                    U8 t; t.u = pp;                                           \
                    float2 fa = __half22float2(t.h[0]);                       \
                    float2 fb = __half22float2(t.h[1]);                       \
                    acc.x += v * fa.x; acc.y += v * fa.y;                     \
                    acc.z += v * fb.x; acc.w += v * fb.y;                     \
                    int kg = kb + (jj) + 1;                                   \
                    while (r_cur < 4 && kg == next_b) FINALIZE_ROW();         \
                }                                                             \
            } while (0)

            for (int j = 0; j < nk; j += 4) {
                uint2 q0 = make_uint2(0u, 0u), q1 = q0, q2 = q0, q3 = q0;
                ISSUE(q0, j + 4); ISSUE(q1, j + 5); ISSUE(q2, j + 6); ISSUE(q3, j + 7);
                CONSUME(p0, j + 0);
                CONSUME(p1, j + 1);
                CONSUME(p2, j + 2);
                CONSUME(p3, j + 3);
                p0 = q0; p1 = q1; p2 = q2; p3 = q3;
            }
#undef ISSUE
#undef CONSUME
        }
#undef FINALIZE_ROW
    }
    __syncthreads();

    // Epilogue: pure LDS + FMA + NT stores (logits already in lg[]).
    // Element bt of row r lives at LDS column (bt&3)*64 + (bt>>2).
    if (ie_ok) {
#pragma unroll
        for (int r = 0; r < 16; ++r) {
            int bt = r * 16 + ty;
            int c = ((bt & 3) << 6) + (bt >> 2);
            __builtin_nontemporal_store(lg[r] + s[tx][c],
                                        &out[(size_t)bt * NN + ie]);  // coalesced over i
        }
    }
}

// ===================== fallback (atomic) path kernels =====================

__global__ void transpose_kernel(const float* __restrict__ logits, float* __restrict__ xT) {
    __shared__ float s[32][33];
    int tx = threadIdx.x & 31;
    int ty = threadIdx.x >> 5;
    int i0  = blockIdx.x * 32;
    int bt0 = blockIdx.y * 32;
    int i = i0 + tx;
#pragma unroll
    for (int r = 0; r < 4; ++r) {
        int bt = bt0 + ty + r * 8;
        if (i < NN) s[ty + r * 8][tx] = logits[(size_t)bt * NN + i];
    }
    __syncthreads();
#pragma unroll
    for (int r = 0; r < 4; ++r) {
        int i2 = i0 + ty + r * 8;
        if (i2 < NN) xT[(size_t)i2 * BT + bt0 + tx] = s[tx][ty + r * 8];
    }
}

__global__ void rowsum_kernel(const int* __restrict__ row, const float* __restrict__ vv,
                              float* __restrict__ row_sum, int E) {
    int e = blockIdx.x * blockDim.x + threadIdx.x;
    if (e < E) atomicAdd(&row_sum[row[e]], vv[e]);
}

__global__ void edge_kernel(const int* __restrict__ row, const int* __restrict__ col,
                            const float* __restrict__ vv, const float* __restrict__ xT,
                            float* __restrict__ acc, int E) {
    int e = blockIdx.x * 4 + (threadIdx.x >> 6);
    if (e >= E) return;
    int lane = threadIdx.x & 63;
    int r = row[e];
    int c = col[e];
    float v = vv[e];
    float4 x4 = ((const float4*)(xT + (size_t)c * BT))[lane];
    float* dst = acc + (size_t)r * BT + lane * 4;
    atomicAdd(dst + 0, v * x4.x);
    atomicAdd(dst + 1, v * x4.y);
    atomicAdd(dst + 2, v * x4.z);
    atomicAdd(dst + 3, v * x4.w);
}

__global__ void finalize_div_kernel(const float* __restrict__ logits, const float* __restrict__ acc,
                                    const float* __restrict__ row_sum, float* __restrict__ out) {
    __shared__ float s[32][33];
    __shared__ float rs[32];
    int tx = threadIdx.x & 31;
    int ty = threadIdx.x >> 5;
    int i0  = blockIdx.x * 32;
    int bt0 = blockIdx.y * 32;
#pragma unroll
    for (int r = 0; r < 4; ++r) {
        int il = ty + r * 8;
        int i = i0 + il;
        if (i < NN) s[il][tx] = acc[(size_t)i * BT + bt0 + tx];
    }
    if (threadIdx.x < 32) {
        int i = i0 + (int)threadIdx.x;
        rs[threadIdx.x] = (i < NN) ? row_sum[i] : 1.0f;
    }
    __syncthreads();
#pragma unroll
    for (int r = 0; r < 4; ++r) {
        int bt = bt0 + ty + r * 8;
        int i = i0 + tx;
        if (i < NN) {
            size_t idx = (size_t)bt * NN + i;
            out[idx] = logits[idx] + s[tx][ty + r * 8] / rs[tx];
        }
    }
}

extern "C" void kernel_launch(void* const* d_in, const int* in_sizes, int n_in,
                              void* d_out, int out_size, void* d_ws, size_t ws_size,
                              hipStream_t stream) {
    const float* logits = (const float*)d_in[0];
    const float* vv     = (const float*)d_in[1];
    const int*   ei     = (const int*)d_in[2];
    const int E = in_sizes[1];
    const int* row = ei;        // edge_index[0]
    const int* col = ei + E;    // edge_index[1]
    float* out = (float*)d_out;

    const size_t accN = (size_t)NN * BT;   // 29,952,000 elems

    const int e_blocks = (E + 255) / 256;

    // CSR-path workspace layout (fp16 xT, packed edges, no accT):
    //   edge_s     : E int2            (8B aligned at ws base)
    //   xT         : accN halves
    //   row_ptr    : NN+1 ints (doubles as count during histogram)
    //   cursor     : NN ints
    //   block_sums : SCAN_NB ints
    const size_t need_csr = (size_t)E * sizeof(int2)
                          + accN * sizeof(__half)
                          + (size_t)(NN + 1 + NN + SCAN_NB) * sizeof(int);

    if (ws_size >= need_csr) {
        int2*   edge_s     = (int2*)d_ws;
        __half* xT         = (__half*)(edge_s + E);
        int*    row_ptr    = (int*)(xT + accN);
        int*    cursor     = row_ptr + (NN + 1);
        int*    block_sums = cursor + NN;

        dim3 tgrid((NN + 31) / 32, BT / 64);          // transpose tiles (32 i x 64 bt)
        const int fuse_blocks = (NN + ROWS_PB - 1) / ROWS_PB;   // 3657

        hipMemsetAsync(row_ptr, 0, (NN + 1) * sizeof(int), stream);
        hist_kernel<<<e_blocks, 256, 0, stream>>>(row, row_ptr, E);
        scan_phase1<<<SCAN_NB, 256, 0, stream>>>(row_ptr, block_sums);
        scan_phase2<<<1, SCAN_P2_T, 0, stream>>>(block_sums, row_ptr);
        scan_phase3<<<SCAN_NB, 256, 0, stream>>>(row_ptr, block_sums, cursor);
        scatter_kernel<<<e_blocks, 256, 0, stream>>>(row, col, vv, cursor, edge_s, E);
        transpose_h_kernel<<<tgrid, 256, 0, stream>>>(logits, xT);
        row_gather_fused_kernel<<<fuse_blocks, 512, 0, stream>>>(row_ptr, edge_s, xT,
                                                                 logits, out);
    } else {
        // Fallback: atomic-scatter path (known-passing, fp32).
        float* acc     = (float*)d_ws;
        float* xT      = acc + accN;
        float* row_sum = xT + accN;
        dim3 tgrid32((NN + 31) / 32, BT / 32);
        hipMemsetAsync(acc, 0, accN * sizeof(float), stream);
        hipMemsetAsync(row_sum, 0, NN * sizeof(float), stream);
        rowsum_kernel<<<e_blocks, 256, 0, stream>>>(row, vv, row_sum, E);
        transpose_kernel<<<tgrid32, 256, 0, stream>>>(logits, xT);
        edge_kernel<<<(E + 3) / 4, 256, 0, stream>>>(row, col, vv, xT, acc, E);
        finalize_div_kernel<<<tgrid32, 256, 0, stream>>>(logits, acc, row_sum, out);
    }
}

// Round 6
// 365.500 us; speedup vs baseline: 1.0660x; 1.0660x over previous
//
#include <hip/hip_runtime.h>
#include <hip/hip_fp16.h>

// Problem constants (fixed by the reference setup):
//   N = 117000 vocab rows, BT = B*T = 4*64 = 256, E = 500000 edges (in_sizes[1])
#define NN 117000
#define BT 256

// Scan decomposition: 115 blocks x 256 threads x 4 elems = 117760 slots >= NN
#define SCAN_CHUNK 1024
#define SCAN_NB ((NN + SCAN_CHUNK - 1) / SCAN_CHUNK)   // 115
#define SCAN_P2_T 128                                   // >= SCAN_NB

// Fused gather+finalize geometry: 32 rows per block, 8 waves (512 threads),
// each wave owns 4 consecutive rows (their CSR edge ranges are contiguous).
#define ROWS_PB 32
#define LDS_STRIDE 257   // odd stride: epilogue reads conflict-free, writes 2-way (free)

union U8 { uint2 u; __half2 h[2]; };

__device__ inline float readlane_f(float x, int l) {
    return __int_as_float(__builtin_amdgcn_readlane(__float_as_int(x), l));
}

// ===================== CSR build =====================

// count[r] += 1 for each edge
__global__ void hist_kernel(const int* __restrict__ row, int* __restrict__ count, int E) {
    int e = blockIdx.x * blockDim.x + threadIdx.x;
    if (e < E) atomicAdd(&count[row[e]], 1);
}

// Phase 1: per-block sum of each 1024-count chunk.
__global__ void scan_phase1(const int* __restrict__ count, int* __restrict__ block_sums) {
    __shared__ int s[256];
    int base = blockIdx.x * SCAN_CHUNK + threadIdx.x * 4;
    int sum = 0;
#pragma unroll
    for (int j = 0; j < 4; ++j) {
        int idx = base + j;
        if (idx < NN) sum += count[idx];
    }
    s[threadIdx.x] = sum;
    __syncthreads();
    for (int off = 128; off > 0; off >>= 1) {
        if (threadIdx.x < off) s[threadIdx.x] += s[threadIdx.x + off];
        __syncthreads();
    }
    if (threadIdx.x == 0) block_sums[blockIdx.x] = s[0];
}

// Phase 2: single small block — exclusive scan of the 115 block sums,
// and write row_ptr[NN] = E.
__global__ void scan_phase2(int* __restrict__ block_sums, int* __restrict__ row_ptr) {
    __shared__ int s[SCAN_P2_T];
    int t = threadIdx.x;
    int v = (t < SCAN_NB) ? block_sums[t] : 0;
    s[t] = v;
    __syncthreads();
    for (int off = 1; off < SCAN_P2_T; off <<= 1) {
        int u = (t >= off) ? s[t - off] : 0;
        __syncthreads();
        s[t] += u;
        __syncthreads();
    }
    if (t < SCAN_NB) block_sums[t] = (t == 0) ? 0 : s[t - 1];  // exclusive offsets
    if (t == SCAN_P2_T - 1) row_ptr[NN] = s[SCAN_NB - 1];      // total == E
}

// Phase 3: in-place exclusive scan of counts within each chunk + block offset.
__global__ void scan_phase3(int* __restrict__ row_ptr, const int* __restrict__ block_offs,
                            int* __restrict__ cursor) {
    __shared__ int s[256];
    int base = blockIdx.x * SCAN_CHUNK + threadIdx.x * 4;
    int v[4];
    int sum = 0;
#pragma unroll
    for (int j = 0; j < 4; ++j) {
        int idx = base + j;
        v[j] = (idx < NN) ? row_ptr[idx] : 0;
        sum += v[j];
    }
    s[threadIdx.x] = sum;
    __syncthreads();
    for (int off = 1; off < 256; off <<= 1) {
        int u = (threadIdx.x >= off) ? s[threadIdx.x - off] : 0;
        __syncthreads();
        s[threadIdx.x] += u;
        __syncthreads();
    }
    int prefix = block_offs[blockIdx.x] + ((threadIdx.x == 0) ? 0 : s[threadIdx.x - 1]);
#pragma unroll
    for (int j = 0; j < 4; ++j) {
        int idx = base + j;
        if (idx < NN) {
            row_ptr[idx] = prefix;
            cursor[idx]  = prefix;
            prefix += v[j];
        }
    }
}

// Scatter edges into row-sorted order as packed {col, vv_bits} int2.
// Order within a row is nondeterministic — only changes fp32 summation order.
__global__ void scatter_kernel(const int* __restrict__ row, const int* __restrict__ col,
                               const float* __restrict__ vv, int* __restrict__ cursor,
                               int2* __restrict__ edge_s, int E) {
    int e = blockIdx.x * blockDim.x + threadIdx.x;
    if (e >= E) return;
    int p = atomicAdd(&cursor[row[e]], 1);
    edge_s[p] = make_int2(col[e], __float_as_int(vv[e]));
}

// ===================== main pipeline =====================

// fp16 transpose: xT[i*BT + bt] = (half)logits[bt*NN + i]
// Plain loads (NOT non-temporal): this read WARMS the LLC with logits, which the
// fused kernel's epilogue re-reads ~100 us later (round-5 NT experiment: -24 us).
__global__ void transpose_h_kernel(const float* __restrict__ logits, __half* __restrict__ xT) {
    __shared__ float s[64][33];   // [bt_local][i_local]
    int tx = threadIdx.x & 31;
    int ty = threadIdx.x >> 5;    // 0..7
    int i0  = blockIdx.x * 32;
    int bt0 = blockIdx.y * 64;
    int i = i0 + tx;
    if (i < NN) {
#pragma unroll
        for (int r = 0; r < 8; ++r) {
            int bt = bt0 + ty + r * 8;
            s[ty + r * 8][tx] = logits[(size_t)bt * NN + i];   // coalesced over i
        }
    }
    __syncthreads();
#pragma unroll
    for (int r = 0; r < 4; ++r) {
        int il = ty + r * 8;
        int i2 = i0 + il;
        if (i2 < NN) {
            __half2 h = __floats2half2_rn(s[2 * tx][il], s[2 * tx + 1][il]);
            ((__half2*)(xT + (size_t)i2 * BT + bt0))[tx] = h;  // coalesced over bt
        }
    }
}

// Fused gather + normalize + transpose + add + store.
// 8 waves x 4 consecutive rows per block; wave streams its contiguous CSR range
// with a 12-DEEP ROLLING gather pipeline (consume p_i -> immediately reissue p_i
// for j+12) running across row boundaries. Avg wave range = 4 rows x 4.3 = ~17
// edges, so ~2 latency waits per wave instead of ~5 (4-deep) — the gather phase
// is latency-bound, not BW-bound (round-4: 34% VALUBusy, 44% of HBM peak).
// __launch_bounds__(512, 8): cap VGPR at 64 so 8 waves/SIMD survive the +24
// pipeline registers.
__global__ void __launch_bounds__(512, 8)
row_gather_fused_kernel(const int* __restrict__ row_ptr,
                        const int2* __restrict__ edge_s,
                        const __half* __restrict__ xT,
                        const float* __restrict__ logits,
                        float* __restrict__ out) {
    __shared__ float s[ROWS_PB][LDS_STRIDE];
    int wave = threadIdx.x >> 6;   // 0..7
    int lane = threadIdx.x & 63;
    int i0 = blockIdx.x * ROWS_PB;
    int iw = i0 + wave * 4;        // first row of this wave
    const uint2* xT2 = (const uint2*)xT;   // 64 uint2 per row (256 halves)

    if (iw < NN) {
        // row_ptr[iw .. iw+4] in one shot (clamped; row_ptr[NN] == E)
        int rp = 0;
        if (lane < 5) {
            int idx = iw + lane;
            if (idx > NN) idx = NN;
            rp = row_ptr[idx];
        }
        int kw0 = __shfl(rp, 0);
        int b0  = __shfl(rp, 1);
        int b1  = __shfl(rp, 2);
        int b2  = __shfl(rp, 3);
        int b3  = __shfl(rp, 4);
        int kw1 = b3;

        float4 acc = make_float4(0.f, 0.f, 0.f, 0.f);
        float rs = 0.f;
        int r_cur = 0;
        int next_b = b0;

#define FINALIZE_ROW() do {                                                   \
            float inv = (rs > 0.f) ? (1.0f / rs) : 0.f;                       \
            int rl = (wave << 2) + r_cur;                                     \
            s[rl][0 * 64 + lane] = acc.x * inv;                               \
            s[rl][1 * 64 + lane] = acc.y * inv;                               \
            s[rl][2 * 64 + lane] = acc.z * inv;                               \
            s[rl][3 * 64 + lane] = acc.w * inv;                               \
            acc = make_float4(0.f, 0.f, 0.f, 0.f);                            \
            rs = 0.f;                                                         \
            ++r_cur;                                                          \
            next_b = (r_cur == 1) ? b1 : ((r_cur == 2) ? b2 : b3);            \
        } while (0)

        // leading empty rows (defensive; setup guarantees none)
        while (r_cur < 4 && next_b == kw0) FINALIZE_ROW();

        for (int kb = kw0; kb < kw1; kb += 64) {
            int nk = min(64, kw1 - kb);
            int2 ed = make_int2(0, 0);
            if (lane < nk) ed = edge_s[kb + lane];   // one coalesced load per chunk
            int   ccol = ed.x;
            float cval = __int_as_float(ed.y);

            uint2 p0, p1, p2, p3, p4, p5, p6, p7, p8, p9, p10, p11;
            p0 = p1 = p2 = p3 = p4 = p5 = p6 = p7 = p8 = p9 = p10 = p11
               = make_uint2(0u, 0u);
#define ISSUE(dst, jj) do {                                                   \
                if ((jj) < nk) {                                              \
                    int cn = __builtin_amdgcn_readlane(ccol, (jj));           \
                    dst = xT2[(size_t)cn * (BT / 4) + lane];                  \
                }                                                             \
            } while (0)
#define CONSUME(pp, jj) do {                                                  \
                if ((jj) < nk) {                                              \
                    float v = readlane_f(cval, (jj));                         \
                    rs += v;                                                  \
                    U8 t; t.u = pp;                                           \
                    float2 fa = __half22float2(t.h[0]);                       \
                    float2 fb = __half22float2(t.h[1]);                       \
                    acc.x += v * fa.x; acc.y += v * fa.y;                     \
                    acc.z += v * fb.x; acc.w += v * fb.y;                     \
                    int kg = kb + (jj) + 1;                                   \
                    while (r_cur < 4 && kg == next_b) FINALIZE_ROW();         \
                }                                                             \
            } while (0)

            // prologue: fill the 12-deep window
            ISSUE(p0, 0);  ISSUE(p1, 1);  ISSUE(p2, 2);  ISSUE(p3, 3);
            ISSUE(p4, 4);  ISSUE(p5, 5);  ISSUE(p6, 6);  ISSUE(p7, 7);
            ISSUE(p8, 8);  ISSUE(p9, 9);  ISSUE(p10, 10); ISSUE(p11, 11);

            // rolling window: consume slot, reissue same slot for j+12
            for (int j = 0; j < nk; j += 12) {
                CONSUME(p0,  j + 0);  ISSUE(p0,  j + 12);
                CONSUME(p1,  j + 1);  ISSUE(p1,  j + 13);
                CONSUME(p2,  j + 2);  ISSUE(p2,  j + 14);
                CONSUME(p3,  j + 3);  ISSUE(p3,  j + 15);
                CONSUME(p4,  j + 4);  ISSUE(p4,  j + 16);
                CONSUME(p5,  j + 5);  ISSUE(p5,  j + 17);
                CONSUME(p6,  j + 6);  ISSUE(p6,  j + 18);
                CONSUME(p7,  j + 7);  ISSUE(p7,  j + 19);
                CONSUME(p8,  j + 8);  ISSUE(p8,  j + 20);
                CONSUME(p9,  j + 9);  ISSUE(p9,  j + 21);
                CONSUME(p10, j + 10); ISSUE(p10, j + 22);
                CONSUME(p11, j + 11); ISSUE(p11, j + 23);
            }
#undef ISSUE
#undef CONSUME
        }
#undef FINALIZE_ROW
    }
    __syncthreads();

    // Epilogue: tx = i_local (0..31), ty selects bt; 16 iterations cover bt=0..255.
    // Element bt of row r lives at LDS column (bt&3)*64 + (bt>>2).
    // Plain loads: logits is LLC-warm from transpose_h (round-5 NT regression).
    int tx = threadIdx.x & 31;
    int ty = threadIdx.x >> 5;   // 0..15
    int i = i0 + tx;
    if (i < NN) {
#pragma unroll
        for (int r = 0; r < 16; ++r) {
            int bt = r * 16 + ty;
            int c = ((bt & 3) << 6) + (bt >> 2);
            size_t idx = (size_t)bt * NN + i;
            out[idx] = logits[idx] + s[tx][c];   // coalesced over i; LDS conflict-free
        }
    }
}

// ===================== fallback (atomic) path kernels =====================

__global__ void transpose_kernel(const float* __restrict__ logits, float* __restrict__ xT) {
    __shared__ float s[32][33];
    int tx = threadIdx.x & 31;
    int ty = threadIdx.x >> 5;
    int i0  = blockIdx.x * 32;
    int bt0 = blockIdx.y * 32;
    int i = i0 + tx;
#pragma unroll
    for (int r = 0; r < 4; ++r) {
        int bt = bt0 + ty + r * 8;
        if (i < NN) s[ty + r * 8][tx] = logits[(size_t)bt * NN + i];
    }
    __syncthreads();
#pragma unroll
    for (int r = 0; r < 4; ++r) {
        int i2 = i0 + ty + r * 8;
        if (i2 < NN) xT[(size_t)i2 * BT + bt0 + tx] = s[tx][ty + r * 8];
    }
}

__global__ void rowsum_kernel(const int* __restrict__ row, const float* __restrict__ vv,
                              float* __restrict__ row_sum, int E) {
    int e = blockIdx.x * blockDim.x + threadIdx.x;
    if (e < E) atomicAdd(&row_sum[row[e]], vv[e]);
}

__global__ void edge_kernel(const int* __restrict__ row, const int* __restrict__ col,
                            const float* __restrict__ vv, const float* __restrict__ xT,
                            float* __restrict__ acc, int E) {
    int e = blockIdx.x * 4 + (threadIdx.x >> 6);
    if (e >= E) return;
    int lane = threadIdx.x & 63;
    int r = row[e];
    int c = col[e];
    float v = vv[e];
    float4 x4 = ((const float4*)(xT + (size_t)c * BT))[lane];
    float* dst = acc + (size_t)r * BT + lane * 4;
    atomicAdd(dst + 0, v * x4.x);
    atomicAdd(dst + 1, v * x4.y);
    atomicAdd(dst + 2, v * x4.z);
    atomicAdd(dst + 3, v * x4.w);
}

__global__ void finalize_div_kernel(const float* __restrict__ logits, const float* __restrict__ acc,
                                    const float* __restrict__ row_sum, float* __restrict__ out) {
    __shared__ float s[32][33];
    __shared__ float rs[32];
    int tx = threadIdx.x & 31;
    int ty = threadIdx.x >> 5;
    int i0  = blockIdx.x * 32;
    int bt0 = blockIdx.y * 32;
#pragma unroll
    for (int r = 0; r < 4; ++r) {
        int il = ty + r * 8;
        int i = i0 + il;
        if (i < NN) s[il][tx] = acc[(size_t)i * BT + bt0 + tx];
    }
    if (threadIdx.x < 32) {
        int i = i0 + (int)threadIdx.x;
        rs[threadIdx.x] = (i < NN) ? row_sum[i] : 1.0f;
    }
    __syncthreads();
#pragma unroll
    for (int r = 0; r < 4; ++r) {
        int bt = bt0 + ty + r * 8;
        int i = i0 + tx;
        if (i < NN) {
            size_t idx = (size_t)bt * NN + i;
            out[idx] = logits[idx] + s[tx][ty + r * 8] / rs[tx];
        }
    }
}

extern "C" void kernel_launch(void* const* d_in, const int* in_sizes, int n_in,
                              void* d_out, int out_size, void* d_ws, size_t ws_size,
                              hipStream_t stream) {
    const float* logits = (const float*)d_in[0];
    const float* vv     = (const float*)d_in[1];
    const int*   ei     = (const int*)d_in[2];
    const int E = in_sizes[1];
    const int* row = ei;        // edge_index[0]
    const int* col = ei + E;    // edge_index[1]
    float* out = (float*)d_out;

    const size_t accN = (size_t)NN * BT;   // 29,952,000 elems

    const int e_blocks = (E + 255) / 256;

    // CSR-path workspace layout (fp16 xT, packed edges, no accT):
    //   edge_s     : E int2            (8B aligned at ws base)
    //   xT         : accN halves
    //   row_ptr    : NN+1 ints (doubles as count during histogram)
    //   cursor     : NN ints
    //   block_sums : SCAN_NB ints
    const size_t need_csr = (size_t)E * sizeof(int2)
                          + accN * sizeof(__half)
                          + (size_t)(NN + 1 + NN + SCAN_NB) * sizeof(int);

    if (ws_size >= need_csr) {
        int2*   edge_s     = (int2*)d_ws;
        __half* xT         = (__half*)(edge_s + E);
        int*    row_ptr    = (int*)(xT + accN);
        int*    cursor     = row_ptr + (NN + 1);
        int*    block_sums = cursor + NN;

        dim3 tgrid((NN + 31) / 32, BT / 64);          // transpose tiles (32 i x 64 bt)
        const int fuse_blocks = (NN + ROWS_PB - 1) / ROWS_PB;   // 3657

        hipMemsetAsync(row_ptr, 0, (NN + 1) * sizeof(int), stream);
        hist_kernel<<<e_blocks, 256, 0, stream>>>(row, row_ptr, E);
        scan_phase1<<<SCAN_NB, 256, 0, stream>>>(row_ptr, block_sums);
        scan_phase2<<<1, SCAN_P2_T, 0, stream>>>(block_sums, row_ptr);
        scan_phase3<<<SCAN_NB, 256, 0, stream>>>(row_ptr, block_sums, cursor);
        scatter_kernel<<<e_blocks, 256, 0, stream>>>(row, col, vv, cursor, edge_s, E);
        transpose_h_kernel<<<tgrid, 256, 0, stream>>>(logits, xT);
        row_gather_fused_kernel<<<fuse_blocks, 512, 0, stream>>>(row_ptr, edge_s, xT,
                                                                 logits, out);
    } else {
        // Fallback: atomic-scatter path (known-passing, fp32).
        float* acc     = (float*)d_ws;
        float* xT      = acc + accN;
        float* row_sum = xT + accN;
        dim3 tgrid32((NN + 31) / 32, BT / 32);
        hipMemsetAsync(acc, 0, accN * sizeof(float), stream);
        hipMemsetAsync(row_sum, 0, NN * sizeof(float), stream);
        rowsum_kernel<<<e_blocks, 256, 0, stream>>>(row, vv, row_sum, E);
        transpose_kernel<<<tgrid32, 256, 0, stream>>>(logits, xT);
        edge_kernel<<<(E + 3) / 4, 256, 0, stream>>>(row, col, vv, xT, acc, E);
        finalize_div_kernel<<<tgrid32, 256, 0, stream>>>(logits, acc, row_sum, out);
    }
}